// Round 4
// baseline (298.341 us; speedup 1.0000x reference)
//
#include <hip/hip_runtime.h>

typedef __attribute__((ext_vector_type(8))) short bf16x8;
typedef __attribute__((ext_vector_type(4))) float f32x4;
typedef unsigned int u32;
typedef unsigned short u16;

constexpr int Bb = 4, S = 2048, D = 1024, H = 16, DK = 64, M = Bb * S;

#if __has_builtin(__builtin_amdgcn_exp2f)
#define EXP2F __builtin_amdgcn_exp2f
#else
#define EXP2F exp2f
#endif

__device__ __forceinline__ u16 f2bf(float f) {
  u32 u = __float_as_uint(f);
  return (u16)((u + 0x7fffu + ((u >> 16) & 1u)) >> 16);
}

__device__ __forceinline__ void gld_lds16(const u16* g, u16* l) {
  __builtin_amdgcn_global_load_lds((const __attribute__((address_space(1))) u32*)g,
                                   (__attribute__((address_space(3))) u32*)l, 16, 0, 0);
}

__global__ void cast_kernel(const float* __restrict__ s, u16* __restrict__ d, int n) {
  int i = (blockIdx.x * blockDim.x + threadIdx.x) * 4;
  if (i >= n) return;
  float4 f = *(const float4*)(s + i);
  ushort4 o;
  o.x = f2bf(f.x); o.y = f2bf(f.y); o.z = f2bf(f.z); o.w = f2bf(f.w);
  *(ushort4*)(d + i) = o;
}

struct CastArgs { const float* s[4]; u16* d[4]; float sc[4]; };
__global__ void cast4_kernel(CastArgs a) {
  int i = (blockIdx.x * blockDim.x + threadIdx.x) * 4;
  int w = i >> 20;
  int off = i & ((1 << 20) - 1);
  float sc = a.sc[w];
  float4 f = *(const float4*)(a.s[w] + off);
  ushort4 o;
  o.x = f2bf(f.x * sc); o.y = f2bf(f.y * sc); o.z = f2bf(f.z * sc); o.w = f2bf(f.w * sc);
  *(ushort4*)(a.d[w] + off) = o;
}

// ---- GEMM core: C[m,n] = sum_k A[m,k]*Bt[n,k], 128x128 tile, BK=64 ----
// K-slot swizzle: LDS granule (row r, slot s) holds global k-granule s^(r&7),
// keeping global_load_lds dest contiguous AND b128 frag reads bank-optimal.
template <bool OUTF32>
__device__ __forceinline__ void gemm_core(const u16* __restrict__ A,
                                          const u16* __restrict__ Bt,
                                          float* __restrict__ Cf, u16* __restrict__ Cb,
                                          int Nn, int Kk, int m0, int n0,
                                          u16* As, u16* Bs) {
  const int tid = threadIdx.x, wave = tid >> 6, lane = tid & 63;
  const int quad = lane >> 4, col = lane & 15;
  const int wm = wave >> 1, wn = wave & 1;

  f32x4 acc[4][4];
#pragma unroll
  for (int i = 0; i < 4; i++)
#pragma unroll
    for (int j = 0; j < 4; j++) acc[i][j] = (f32x4){0.f, 0.f, 0.f, 0.f};

  for (int k0 = 0; k0 < Kk; k0 += 64) {
#pragma unroll
    for (int j = 0; j < 4; j++) {
      int g = (wave * 4 + j) * 64;   // wave-uniform granule base
      int gl = g + lane;
      int r = gl >> 3, sl = gl & 7;
      int kof = (sl ^ (r & 7)) * 8;
      const u16* ga = A + (size_t)(m0 + r) * Kk + k0 + kof;
      gld_lds16(ga, &As[g * 8]);
      const u16* gb = Bt + (size_t)(n0 + r) * Kk + k0 + kof;
      gld_lds16(gb, &Bs[g * 8]);
    }
    __syncthreads();
#pragma unroll
    for (int kb = 0; kb < 2; kb++) {
      bf16x8 af[4], bfr[4];
#pragma unroll
      for (int mi = 0; mi < 4; mi++) {
        int R = wm * 64 + mi * 16 + col;
        af[mi] = *(const bf16x8*)&As[R * 64 + (((kb * 4 + quad) ^ (R & 7)) << 3)];
      }
#pragma unroll
      for (int ni = 0; ni < 4; ni++) {
        int R = wn * 64 + ni * 16 + col;
        bfr[ni] = *(const bf16x8*)&Bs[R * 64 + (((kb * 4 + quad) ^ (R & 7)) << 3)];
      }
#pragma unroll
      for (int mi = 0; mi < 4; mi++)
#pragma unroll
        for (int ni = 0; ni < 4; ni++)
          acc[mi][ni] = __builtin_amdgcn_mfma_f32_16x16x32_bf16(af[mi], bfr[ni], acc[mi][ni], 0, 0, 0);
    }
    __syncthreads();
  }
#pragma unroll
  for (int mi = 0; mi < 4; mi++)
#pragma unroll
    for (int ni = 0; ni < 4; ni++)
#pragma unroll
      for (int r = 0; r < 4; r++) {
        int row = m0 + wm * 64 + mi * 16 + quad * 4 + r;
        int cc = n0 + wn * 64 + ni * 16 + col;
        float v = acc[mi][ni][r];
        if (OUTF32) Cf[(size_t)row * Nn + cc] = v;
        else Cb[(size_t)row * Nn + cc] = f2bf(v);
      }
}

struct QkvArgs { const u16* bt[3]; u16* c[3]; };
__global__ __launch_bounds__(256) void gemm_qkv(const u16* __restrict__ A, QkvArgs q) {
  __shared__ __align__(16) u16 As[128 * 64];
  __shared__ __align__(16) u16 Bs[128 * 64];
  int sel = blockIdx.x >> 3;
  int n0 = (blockIdx.x & 7) * 128, m0 = blockIdx.y * 128;
  gemm_core<false>(A, q.bt[sel], nullptr, q.c[sel], D, D, m0, n0, As, Bs);
}

__global__ __launch_bounds__(256) void gemm_f32(const u16* __restrict__ A,
                                                const u16* __restrict__ Bt,
                                                float* __restrict__ C) {
  __shared__ __align__(16) u16 As[128 * 64];
  __shared__ __align__(16) u16 Bs[128 * 64];
  gemm_core<true>(A, Bt, C, nullptr, D, D, blockIdx.y * 128, blockIdx.x * 128, As, Bs);
}

// ---- flash attention, causal ----
// 128 q-rows/block, 4 waves x 32 rows. One barrier/iter. K direct to regs
// (L1 broadcast across waves). V double-buffered regs->LDS transposed.
// Q pre-scaled by 0.125*log2e in the Wq cast => p = exp2(sacc) raw.
// Row sums via ones-MFMA on stored bf16 P (exact consistency, no shuffles).
__global__ __launch_bounds__(256) void attn_kernel(const u16* __restrict__ Q,
                                                   const u16* __restrict__ K,
                                                   const u16* __restrict__ V,
                                                   u16* __restrict__ O) {
  __shared__ __align__(16) u16 Vt[2][64 * 64];   // V^T [d][key-swizzled]
  __shared__ __align__(16) u16 Pw[4][32 * 64];   // per-wave P [q][key-swizzled]
  const int tid = threadIdx.x, wave = tid >> 6, lane = tid & 63;
  const int quad = lane >> 4, col = lane & 15;
  const int bh = blockIdx.x, b = bh >> 4, h = bh & 15;
  // per-CU balance under round-robin: y-slots {a,a+4,a+8,a+12} -> qb {a,7-a,8+a,15-a}
  const int ya = blockIdx.y & 3, yk = blockIdx.y >> 2;
  const int qb = (yk == 0) ? ya : (yk == 1) ? 7 - ya : (yk == 2) ? 8 + ya : 15 - ya;
  const size_t base = (size_t)b * S * D + h * DK;
  const int qw = qb * 128 + wave * 32;

  bf16x8 aq[2][2];
#pragma unroll
  for (int mi = 0; mi < 2; mi++)
#pragma unroll
    for (int kb = 0; kb < 2; kb++)
      aq[mi][kb] = *(const bf16x8*)(Q + base + (size_t)(qw + mi * 16 + col) * D + kb * 32 + quad * 8);

  f32x4 ao[2][4], lacc[2];
#pragma unroll
  for (int mi = 0; mi < 2; mi++) {
    lacc[mi] = (f32x4){0.f, 0.f, 0.f, 0.f};
#pragma unroll
    for (int dg = 0; dg < 4; dg++) ao[mi][dg] = (f32x4){0.f, 0.f, 0.f, 0.f};
  }
  bf16x8 bones;
#pragma unroll
  for (int e = 0; e < 8; e++) bones[e] = (short)0x3F80;  // bf16 1.0

  const int vkey = tid >> 2;        // 0..63
  const int vdof = (tid & 3) * 16;  // 0,16,32,48
  const int nkt = 2 * qb + 2;       // always even

  bf16x8 vA0, vA1, vB0, vB1;
  {
    const u16* vp = V + base + (size_t)vkey * D + vdof;
    vA0 = *(const bf16x8*)vp; vA1 = *(const bf16x8*)(vp + 8);
  }
  {
    const u16* vp = V + base + (size_t)(64 + vkey) * D + vdof;  // nkt >= 2 always
    vB0 = *(const bf16x8*)vp; vB1 = *(const bf16x8*)(vp + 8);
  }

  auto vstage = [&](int buf, bf16x8 v0, bf16x8 v1) {
#pragma unroll
    for (int g = 0; g < 2; g++) {
      int dof = vdof + g * 8;
      int sw = (((vkey >> 3) ^ (dof >> 3)) & 7) * 8 + (vkey & 7);
      bf16x8 vv = g ? v1 : v0;
#pragma unroll
      for (int e = 0; e < 8; e++) Vt[buf][(dof + e) * 64 + sw] = (u16)vv[e];
    }
  };
  vstage(0, vA0, vA1);

  auto body = [&](int kt, bool ph) {
    __syncthreads();  // drains prev-iter V global loads + publishes Vt writes
    const int bf = ph ? 1 : 0, nb = bf ^ 1;
    const bool active = (kt * 64 <= qw + 31);  // wave-uniform
    bf16x8 bk0[4], bk1[4];
    if (active) {  // issue K loads ASAP (L1-shared across the 4 waves)
#pragma unroll
      for (int n16 = 0; n16 < 4; n16++) {
        const u16* kp = K + base + (size_t)(kt * 64 + n16 * 16 + col) * D + quad * 8;
        bk0[n16] = *(const bf16x8*)kp;
        bk1[n16] = *(const bf16x8*)(kp + 32);
      }
    }
    if (kt + 1 < nkt) {
      vstage(nb, ph ? vA0 : vB0, ph ? vA1 : vB1);
      if (kt + 2 < nkt) {
        const u16* vp = V + base + (size_t)((kt + 2) * 64 + vkey) * D + vdof;
        if (ph) { vB0 = *(const bf16x8*)vp; vB1 = *(const bf16x8*)(vp + 8); }
        else    { vA0 = *(const bf16x8*)vp; vA1 = *(const bf16x8*)(vp + 8); }
      }
    }
    if (!active) return;
    // QK^T
    f32x4 sacc[2][4];
#pragma unroll
    for (int mi = 0; mi < 2; mi++)
#pragma unroll
      for (int n16 = 0; n16 < 4; n16++) sacc[mi][n16] = (f32x4){0.f, 0.f, 0.f, 0.f};
#pragma unroll
    for (int mi = 0; mi < 2; mi++)
#pragma unroll
      for (int n16 = 0; n16 < 4; n16++) {
        sacc[mi][n16] = __builtin_amdgcn_mfma_f32_16x16x32_bf16(aq[mi][0], bk0[n16], sacc[mi][n16], 0, 0, 0);
        sacc[mi][n16] = __builtin_amdgcn_mfma_f32_16x16x32_bf16(aq[mi][1], bk1[n16], sacc[mi][n16], 0, 0, 0);
      }
    const bool full = (kt * 64 + 63) <= qw;  // wave-uniform: no masking needed
    // p = exp2(s); store truncated bf16 (d16_hi); l comes from ones-MFMA later
#pragma unroll
    for (int mi = 0; mi < 2; mi++)
#pragma unroll
      for (int r = 0; r < 4; r++) {
        int qloc = mi * 16 + quad * 4 + r;
        int qs = quad << 1;
#pragma unroll
        for (int n16 = 0; n16 < 4; n16++) {
          float p = EXP2F(sacc[mi][n16][r]);
          if (!full) {
            int kg = kt * 64 + n16 * 16 + col;
            p = (kg > qw + qloc) ? 0.f : p;
          }
          int kgl = n16 * 16 + col;
          int perm = ((kgl >> 3) ^ qs) & 7;
          Pw[wave][qloc * 64 + perm * 8 + (kgl & 7)] = (u16)(__float_as_uint(p) >> 16);
        }
      }
    // PV + row-sum (same-wave LDS write->read: no barrier)
    bf16x8 bv[2][4];
#pragma unroll
    for (int kb = 0; kb < 2; kb++)
#pragma unroll
      for (int dg = 0; dg < 4; dg++) {
        int d3 = (dg * 2 + (col >> 3)) & 7;
        bv[kb][dg] = *(const bf16x8*)&Vt[bf][(dg * 16 + col) * 64 + (((kb * 4 + quad) ^ d3) << 3)];
      }
#pragma unroll
    for (int mi = 0; mi < 2; mi++) {
      int qs2 = ((col >> 2) & 3) << 1;
      bf16x8 ap0 = *(const bf16x8*)&Pw[wave][(mi * 16 + col) * 64 + (((quad ^ qs2) & 7) << 3)];
      bf16x8 ap1 = *(const bf16x8*)&Pw[wave][(mi * 16 + col) * 64 + ((((4 + quad) ^ qs2) & 7) << 3)];
#pragma unroll
      for (int dg = 0; dg < 4; dg++) {
        ao[mi][dg] = __builtin_amdgcn_mfma_f32_16x16x32_bf16(ap0, bv[0][dg], ao[mi][dg], 0, 0, 0);
        ao[mi][dg] = __builtin_amdgcn_mfma_f32_16x16x32_bf16(ap1, bv[1][dg], ao[mi][dg], 0, 0, 0);
      }
      lacc[mi] = __builtin_amdgcn_mfma_f32_16x16x32_bf16(ap0, bones, lacc[mi], 0, 0, 0);
      lacc[mi] = __builtin_amdgcn_mfma_f32_16x16x32_bf16(ap1, bones, lacc[mi], 0, 0, 0);
    }
  };

  for (int kt = 0; kt < nkt; kt += 2) {
    body(kt, false);
    body(kt + 1, true);
  }

#pragma unroll
  for (int mi = 0; mi < 2; mi++)
#pragma unroll
    for (int r = 0; r < 4; r++) {
      float inv = 1.f / lacc[mi][r];
      int q = qw + mi * 16 + quad * 4 + r;
#pragma unroll
      for (int dg = 0; dg < 4; dg++)
        O[base + (size_t)q * D + dg * 16 + col] = f2bf(ao[mi][dg][r] * inv);
    }
}

extern "C" void kernel_launch(void* const* d_in, const int* in_sizes, int n_in,
                              void* d_out, int out_size, void* d_ws, size_t ws_size,
                              hipStream_t stream) {
  const float* x  = (const float*)d_in[0];
  const float* Wq = (const float*)d_in[1];
  const float* Wk = (const float*)d_in[2];
  const float* Wv = (const float*)d_in[3];
  const float* Wo = (const float*)d_in[4];

  u16* xb  = (u16*)d_ws;
  u16* wqb = xb + (size_t)M * D;
  u16* wkb = wqb + (size_t)D * D;
  u16* wvb = wkb + (size_t)D * D;
  u16* wob = wvb + (size_t)D * D;
  u16* Qb  = wob + (size_t)D * D;
  u16* Kb  = Qb + (size_t)M * D;
  u16* Vb  = Kb + (size_t)M * D;
  u16* Ab  = xb;  // x dead after projections

  cast_kernel<<<M * D / 1024, 256, 0, stream>>>(x, xb, M * D);
  CastArgs ca;
  ca.s[0] = Wq; ca.s[1] = Wk; ca.s[2] = Wv; ca.s[3] = Wo;
  ca.d[0] = wqb; ca.d[1] = wkb; ca.d[2] = wvb; ca.d[3] = wob;
  ca.sc[0] = 0.18033688011112042f;  // 0.125 * log2(e) folded into Wq
  ca.sc[1] = 1.f; ca.sc[2] = 1.f; ca.sc[3] = 1.f;
  cast4_kernel<<<4 * D * D / 1024, 256, 0, stream>>>(ca);

  QkvArgs qa;
  qa.bt[0] = wqb; qa.bt[1] = wkb; qa.bt[2] = wvb;
  qa.c[0] = Qb; qa.c[1] = Kb; qa.c[2] = Vb;
  gemm_qkv<<<dim3(24, M / 128), 256, 0, stream>>>(xb, qa);

  attn_kernel<<<dim3(Bb * H, S / 128), 256, 0, stream>>>(Qb, Kb, Vb, Ab);

  gemm_f32<<<dim3(D / 128, M / 128), 256, 0, stream>>>(Ab, wob, (float*)d_out);
}

// Round 5
// 266.449 us; speedup vs baseline: 1.1197x; 1.1197x over previous
//
#include <hip/hip_runtime.h>

typedef __attribute__((ext_vector_type(8))) short bf16x8;
typedef __attribute__((ext_vector_type(4))) float f32x4;
typedef unsigned int u32;
typedef unsigned short u16;

constexpr int Bb = 4, S = 2048, D = 1024, H = 16, DK = 64, M = Bb * S;

#if __has_builtin(__builtin_amdgcn_exp2f)
#define EXP2F __builtin_amdgcn_exp2f
#else
#define EXP2F exp2f
#endif

__device__ __forceinline__ u16 f2bf(float f) {
  u32 u = __float_as_uint(f);
  return (u16)((u + 0x7fffu + ((u >> 16) & 1u)) >> 16);
}

__device__ __forceinline__ void gld_lds16(const u16* g, u16* l) {
  __builtin_amdgcn_global_load_lds((const __attribute__((address_space(1))) u32*)g,
                                   (__attribute__((address_space(3))) u32*)l, 16, 0, 0);
}

__global__ void cast_kernel(const float* __restrict__ s, u16* __restrict__ d, int n) {
  int i = (blockIdx.x * blockDim.x + threadIdx.x) * 4;
  if (i >= n) return;
  float4 f = *(const float4*)(s + i);
  ushort4 o;
  o.x = f2bf(f.x); o.y = f2bf(f.y); o.z = f2bf(f.z); o.w = f2bf(f.w);
  *(ushort4*)(d + i) = o;
}

struct CastArgs { const float* s[4]; u16* d[4]; float sc[4]; };
__global__ void cast4_kernel(CastArgs a) {
  int i = (blockIdx.x * blockDim.x + threadIdx.x) * 4;
  int w = i >> 20;
  int off = i & ((1 << 20) - 1);
  float sc = a.sc[w];
  float4 f = *(const float4*)(a.s[w] + off);
  ushort4 o;
  o.x = f2bf(f.x * sc); o.y = f2bf(f.y * sc); o.z = f2bf(f.z * sc); o.w = f2bf(f.w * sc);
  *(ushort4*)(a.d[w] + off) = o;
}

// ---- GEMM core: C[m,n] = sum_k A[m,k]*Bt[n,k], 128x128 tile, BK=64 ----
template <bool OUTF32>
__device__ __forceinline__ void gemm_core(const u16* __restrict__ A,
                                          const u16* __restrict__ Bt,
                                          float* __restrict__ Cf, u16* __restrict__ Cb,
                                          int Nn, int Kk, int m0, int n0,
                                          u16* As, u16* Bs) {
  const int tid = threadIdx.x, wave = tid >> 6, lane = tid & 63;
  const int quad = lane >> 4, col = lane & 15;
  const int wm = wave >> 1, wn = wave & 1;

  f32x4 acc[4][4];
#pragma unroll
  for (int i = 0; i < 4; i++)
#pragma unroll
    for (int j = 0; j < 4; j++) acc[i][j] = (f32x4){0.f, 0.f, 0.f, 0.f};

  for (int k0 = 0; k0 < Kk; k0 += 64) {
#pragma unroll
    for (int j = 0; j < 4; j++) {
      int g = (wave * 4 + j) * 64;
      int gl = g + lane;
      int r = gl >> 3, sl = gl & 7;
      int kof = (sl ^ (r & 7)) * 8;
      const u16* ga = A + (size_t)(m0 + r) * Kk + k0 + kof;
      gld_lds16(ga, &As[g * 8]);
      const u16* gb = Bt + (size_t)(n0 + r) * Kk + k0 + kof;
      gld_lds16(gb, &Bs[g * 8]);
    }
    __syncthreads();
#pragma unroll
    for (int kb = 0; kb < 2; kb++) {
      bf16x8 af[4], bfr[4];
#pragma unroll
      for (int mi = 0; mi < 4; mi++) {
        int R = wm * 64 + mi * 16 + col;
        af[mi] = *(const bf16x8*)&As[R * 64 + (((kb * 4 + quad) ^ (R & 7)) << 3)];
      }
#pragma unroll
      for (int ni = 0; ni < 4; ni++) {
        int R = wn * 64 + ni * 16 + col;
        bfr[ni] = *(const bf16x8*)&Bs[R * 64 + (((kb * 4 + quad) ^ (R & 7)) << 3)];
      }
#pragma unroll
      for (int mi = 0; mi < 4; mi++)
#pragma unroll
        for (int ni = 0; ni < 4; ni++)
          acc[mi][ni] = __builtin_amdgcn_mfma_f32_16x16x32_bf16(af[mi], bfr[ni], acc[mi][ni], 0, 0, 0);
    }
    __syncthreads();
  }
#pragma unroll
  for (int mi = 0; mi < 4; mi++)
#pragma unroll
    for (int ni = 0; ni < 4; ni++)
#pragma unroll
      for (int r = 0; r < 4; r++) {
        int row = m0 + wm * 64 + mi * 16 + quad * 4 + r;
        int cc = n0 + wn * 64 + ni * 16 + col;
        float v = acc[mi][ni][r];
        if (OUTF32) Cf[(size_t)row * Nn + cc] = v;
        else Cb[(size_t)row * Nn + cc] = f2bf(v);
      }
}

struct QkvArgs { const u16* bt[3]; u16* c[3]; };
__global__ __launch_bounds__(256) void gemm_qkv(const u16* __restrict__ A, QkvArgs q) {
  __shared__ __align__(16) u16 As[128 * 64];
  __shared__ __align__(16) u16 Bs[128 * 64];
  int sel = blockIdx.x >> 3;
  int n0 = (blockIdx.x & 7) * 128, m0 = blockIdx.y * 128;
  gemm_core<false>(A, q.bt[sel], nullptr, q.c[sel], D, D, m0, n0, As, Bs);
}

__global__ __launch_bounds__(256) void gemm_f32(const u16* __restrict__ A,
                                                const u16* __restrict__ Bt,
                                                float* __restrict__ C) {
  __shared__ __align__(16) u16 As[128 * 64];
  __shared__ __align__(16) u16 Bs[128 * 64];
  gemm_core<true>(A, Bt, C, nullptr, D, D, blockIdx.y * 128, blockIdx.x * 128, As, Bs);
}

// ---- flash attention, causal ----
// Each block: a PAIR of q-blocks (15-p, p) => exactly 34 k-tile iters/block,
// perfectly uniform grid of 512 blocks (no dispatch-order assumptions).
// Per iter one barrier. K double-buffered in LDS via global_load_lds DMA,
// prefetched right after the barrier (full iteration of slack). V double-
// buffered regs->LDS transposed+swizzled, packed u32 writes (bank-free).
// Q pre-scaled by 0.125*log2e => p = exp2(sacc) raw; trunc-store bf16 P;
// row sums via ones-MFMA (no cross-lane shuffles in the loop).
__global__ __launch_bounds__(256) void attn_kernel(const u16* __restrict__ Q,
                                                   const u16* __restrict__ K,
                                                   const u16* __restrict__ V,
                                                   u16* __restrict__ O) {
  __shared__ __align__(16) u16 Ks[2][2][64 * 32];  // [buf][d-half][key*32+d]
  __shared__ __align__(16) u16 Vt[2][64 * 64];     // [buf] V^T [d][key-swizzled]
  __shared__ __align__(16) u16 Pw[4][32 * 64];     // per-wave P [q][key-swizzled]
  const int tid = threadIdx.x, wave = tid >> 6, lane = tid & 63;
  const int quad = lane >> 4, col = lane & 15;
  const int bh = blockIdx.x, b = bh >> 4, h = bh & 15;
  const int pair = blockIdx.y;  // 0..7
  const size_t base = (size_t)b * S * D + h * DK;

  // V staging distribution: thread handles keys (vk0, vk0+1) x 8 d's
  const int vk0 = (tid & 31) * 2;
  const int vdg = tid >> 5;  // d-group 0..7

  bf16x8 bones;
#pragma unroll
  for (int e = 0; e < 8; e++) bones[e] = (short)0x3F80;  // bf16 1.0

  for (int half = 0; half < 2; half++) {
    const int qb = half ? pair : 15 - pair;
    const int qw = qb * 128 + wave * 32;
    const int nkt = 2 * qb + 2;  // even

    bf16x8 aq[2][2];
#pragma unroll
    for (int mi = 0; mi < 2; mi++)
#pragma unroll
      for (int kb = 0; kb < 2; kb++)
        aq[mi][kb] = *(const bf16x8*)(Q + base + (size_t)(qw + mi * 16 + col) * D + kb * 32 + quad * 8);

    f32x4 ao[2][4], lacc[2];
#pragma unroll
    for (int mi = 0; mi < 2; mi++) {
      lacc[mi] = (f32x4){0.f, 0.f, 0.f, 0.f};
#pragma unroll
      for (int dg = 0; dg < 4; dg++) ao[mi][dg] = (f32x4){0.f, 0.f, 0.f, 0.f};
    }

    // regs A hold even V-tiles, regs B hold odd V-tiles
    bf16x8 vA0, vA1, vB0, vB1;
    {
      const u16* vp = V + base + (size_t)vk0 * D + vdg * 8;
      vA0 = *(const bf16x8*)vp; vA1 = *(const bf16x8*)(vp + D);
    }
    __syncthreads();  // previous half's LDS readers done before restaging
    {  // DMA K(0) -> Ks[0]
      int c = tid, cb = wave * 64;
      const u16* g0 = K + base + (size_t)(c >> 2) * D + (c & 3) * 8;
      gld_lds16(g0, &Ks[0][0][cb * 8]);
      gld_lds16(g0 + 32, &Ks[0][1][cb * 8]);
    }
    auto vstage = [&](int buf, bf16x8 r0, bf16x8 r1) {
      int kgrp = vk0 >> 3, kin = vk0 & 7;
      int perm = (kgrp ^ vdg) & 7;
#pragma unroll
      for (int e = 0; e < 8; e++) {
        u32 val = ((u32)(u16)r0[e]) | ((u32)(u16)r1[e] << 16);
        *(u32*)&Vt[buf][(vdg * 8 + e) * 64 + perm * 8 + kin] = val;
      }
    };
    vstage(0, vA0, vA1);
    {  // V(1) -> B (nkt >= 2 always)
      const u16* vp = V + base + (size_t)(64 + vk0) * D + vdg * 8;
      vB0 = *(const bf16x8*)vp; vB1 = *(const bf16x8*)(vp + D);
    }

    for (int kt = 0; kt < nkt; kt++) {
      const int bf = kt & 1, nb = bf ^ 1, ph = kt & 1;
      __syncthreads();  // drains K(kt) DMA + V(kt+1) regs; publishes Vt[bf]
      const bool active = (kt * 64 <= qw + 31);  // wave-uniform
      if (kt + 1 < nkt) {
        {  // prefetch K(kt+1) -> Ks[nb] (a full iteration to land)
          int c = tid, cb = wave * 64;
          const u16* g0 = K + base + (size_t)((kt + 1) * 64 + (c >> 2)) * D + (c & 3) * 8;
          gld_lds16(g0, &Ks[nb][0][cb * 8]);
          gld_lds16(g0 + 32, &Ks[nb][1][cb * 8]);
        }
        // stage V(kt+1): odd tiles from B, even from A
        vstage(nb, ph ? vA0 : vB0, ph ? vA1 : vB1);
        if (kt + 2 < nkt) {  // V(kt+2) -> (even ? A : B)
          const u16* vp = V + base + (size_t)((kt + 2) * 64 + vk0) * D + vdg * 8;
          if (ph) { vB0 = *(const bf16x8*)vp; vB1 = *(const bf16x8*)(vp + D); }
          else    { vA0 = *(const bf16x8*)vp; vA1 = *(const bf16x8*)(vp + D); }
        }
      }
      if (!active) continue;
      // QK^T from Ks[bf]
      bf16x8 bk0[4], bk1[4];
#pragma unroll
      for (int n16 = 0; n16 < 4; n16++) {
        bk0[n16] = *(const bf16x8*)&Ks[bf][0][(n16 * 16 + col) * 32 + quad * 8];
        bk1[n16] = *(const bf16x8*)&Ks[bf][1][(n16 * 16 + col) * 32 + quad * 8];
      }
      f32x4 sacc[2][4];
#pragma unroll
      for (int mi = 0; mi < 2; mi++)
#pragma unroll
        for (int n16 = 0; n16 < 4; n16++) sacc[mi][n16] = (f32x4){0.f, 0.f, 0.f, 0.f};
#pragma unroll
      for (int mi = 0; mi < 2; mi++)
#pragma unroll
        for (int n16 = 0; n16 < 4; n16++) {
          sacc[mi][n16] = __builtin_amdgcn_mfma_f32_16x16x32_bf16(aq[mi][0], bk0[n16], sacc[mi][n16], 0, 0, 0);
          sacc[mi][n16] = __builtin_amdgcn_mfma_f32_16x16x32_bf16(aq[mi][1], bk1[n16], sacc[mi][n16], 0, 0, 0);
        }
      const bool full = (kt * 64 + 63) <= qw;  // wave-uniform: no masking
      // p = exp2(s); trunc-store bf16 into swizzled Pw
#pragma unroll
      for (int mi = 0; mi < 2; mi++)
#pragma unroll
        for (int r = 0; r < 4; r++) {
          int qloc = mi * 16 + quad * 4 + r;
          int qs = quad << 1;
#pragma unroll
          for (int n16 = 0; n16 < 4; n16++) {
            float p = EXP2F(sacc[mi][n16][r]);
            if (!full) {
              int kg = kt * 64 + n16 * 16 + col;
              p = (kg > qw + qloc) ? 0.f : p;
            }
            int kgl = n16 * 16 + col;
            int perm = ((kgl >> 3) ^ qs) & 7;
            Pw[wave][qloc * 64 + perm * 8 + (kgl & 7)] = (u16)(__float_as_uint(p) >> 16);
          }
        }
      // PV + ones-MFMA row sums (same-wave LDS write->read, no barrier)
      bf16x8 bv[2][4];
#pragma unroll
      for (int kb = 0; kb < 2; kb++)
#pragma unroll
        for (int dg = 0; dg < 4; dg++) {
          int d3 = (dg * 2 + (col >> 3)) & 7;
          bv[kb][dg] = *(const bf16x8*)&Vt[bf][(dg * 16 + col) * 64 + (((kb * 4 + quad) ^ d3) << 3)];
        }
#pragma unroll
      for (int mi = 0; mi < 2; mi++) {
        int qs2 = ((col >> 2) & 3) << 1;
        bf16x8 ap0 = *(const bf16x8*)&Pw[wave][(mi * 16 + col) * 64 + (((quad ^ qs2) & 7) << 3)];
        bf16x8 ap1 = *(const bf16x8*)&Pw[wave][(mi * 16 + col) * 64 + ((((4 + quad) ^ qs2) & 7) << 3)];
#pragma unroll
        for (int dg = 0; dg < 4; dg++) {
          ao[mi][dg] = __builtin_amdgcn_mfma_f32_16x16x32_bf16(ap0, bv[0][dg], ao[mi][dg], 0, 0, 0);
          ao[mi][dg] = __builtin_amdgcn_mfma_f32_16x16x32_bf16(ap1, bv[1][dg], ao[mi][dg], 0, 0, 0);
        }
        lacc[mi] = __builtin_amdgcn_mfma_f32_16x16x32_bf16(ap0, bones, lacc[mi], 0, 0, 0);
        lacc[mi] = __builtin_amdgcn_mfma_f32_16x16x32_bf16(ap1, bones, lacc[mi], 0, 0, 0);
      }
    }
    // epilogue: normalize + write O
#pragma unroll
    for (int mi = 0; mi < 2; mi++)
#pragma unroll
      for (int r = 0; r < 4; r++) {
        float inv = 1.f / lacc[mi][r];
        int q = qw + mi * 16 + quad * 4 + r;
#pragma unroll
        for (int dg = 0; dg < 4; dg++)
          O[base + (size_t)q * D + dg * 16 + col] = f2bf(ao[mi][dg][r] * inv);
      }
  }
}

extern "C" void kernel_launch(void* const* d_in, const int* in_sizes, int n_in,
                              void* d_out, int out_size, void* d_ws, size_t ws_size,
                              hipStream_t stream) {
  const float* x  = (const float*)d_in[0];
  const float* Wq = (const float*)d_in[1];
  const float* Wk = (const float*)d_in[2];
  const float* Wv = (const float*)d_in[3];
  const float* Wo = (const float*)d_in[4];

  u16* xb  = (u16*)d_ws;
  u16* wqb = xb + (size_t)M * D;
  u16* wkb = wqb + (size_t)D * D;
  u16* wvb = wkb + (size_t)D * D;
  u16* wob = wvb + (size_t)D * D;
  u16* Qb  = wob + (size_t)D * D;
  u16* Kb  = Qb + (size_t)M * D;
  u16* Vb  = Kb + (size_t)M * D;
  u16* Ab  = xb;  // x dead after projections

  cast_kernel<<<M * D / 1024, 256, 0, stream>>>(x, xb, M * D);
  CastArgs ca;
  ca.s[0] = Wq; ca.s[1] = Wk; ca.s[2] = Wv; ca.s[3] = Wo;
  ca.d[0] = wqb; ca.d[1] = wkb; ca.d[2] = wvb; ca.d[3] = wob;
  ca.sc[0] = 0.18033688011112042f;  // 0.125 * log2(e) folded into Wq
  ca.sc[1] = 1.f; ca.sc[2] = 1.f; ca.sc[3] = 1.f;
  cast4_kernel<<<4 * D * D / 1024, 256, 0, stream>>>(ca);

  QkvArgs qa;
  qa.bt[0] = wqb; qa.bt[1] = wkb; qa.bt[2] = wvb;
  qa.c[0] = Qb; qa.c[1] = Kb; qa.c[2] = Vb;
  gemm_qkv<<<dim3(24, M / 128), 256, 0, stream>>>(xb, qa);

  attn_kernel<<<dim3(Bb * H, 8), 256, 0, stream>>>(Qb, Kb, Vb, Ab);

  gemm_f32<<<dim3(D / 128, M / 128), 256, 0, stream>>>(Ab, wob, (float*)d_out);
}